// Round 4
// baseline (115.784 us; speedup 1.0000x reference)
//
#include <hip/hip_runtime.h>
#include <stdint.h>

// Problem constants (fixed by the reference): x is (128,1,512,512) fp32, k=2048.
#define B        128
#define ROW_N    262144                 // 512*512 elements per row
#define THREADS  256
#define BLOCKS_PER_ROW 16
#define BLK_CHUNK (ROW_N / BLOCKS_PER_ROW)   // 16384 floats per block
#define WAVE_CHUNK 4096                      // floats per wave (4 waves/block)
#define LANE_CAP 16                          // per-lane candidate slots (mean 2.9, P(>=16)~1e-6)

// Speculative exact pre-filter: keep ALL elements with |x| >= 2.0.
// For the fixed N(0,1) input: k-th |x| ~= 2.66; >=2.0 population ~11.9k +- 107
// per row. n >= K guarantees the exact top-k lies within the candidate set.
// Any violation (lane cap, row cap, n < K) flags the row -> exact fallback.
#define B0_BITS  0x40000000u  // bit pattern of 2.0f (abs-bits compare)
#define CAND_CAP 16384        // per-row candidate capacity (+41 sigma)
#define FKSHIFT  17           // 14-bit fine key for tie resolution
#define FB0      8192         // (B0_BITS >> FKSHIFT)
#define NFB      8192         // fine buckets [8192, 16384)
#define TIE_CAP  2048         // ties in one fine bucket (mean ~190)
#define THREADS_SS 512        // select_scatter block size
// fallback (normally never runs)
#define KSHIFT   19
#define NBUCKET  4096
#define FB_TIE_CAP 4096

// workspace layout (bytes)
#define OFF_CNT  0                         // per-row candidate counters (B u32)
#define OFF_OFL  512                       // per-row overflow flags (B u32)
#define OFF_FLG  1024                      // per-row fallback flag (B int)
#define OFF_CAND 4096                      // B * CAND_CAP * uint2 = 16 MiB
#define MEMSET_BYTES 1536

// R4: evidence from R3 — harness fill writes 536 MB @ 6.83 TB/s (write path
// is fine); our read+compact scan is ~80 us for 134 MB (~1.7 TB/s) and
// rate-invariant across all memory-schedule changes (R0-R3). Remaining
// suspect: the per-element ballot -> SALU readback -> EXEC-divergent if(pred),
// 64x per wave. This round: (a) zero-fill via hipMemsetAsync (proven 6.8 TB/s
// path); (b) branchless per-lane compaction scan: unconditional ds_write to a
// per-lane LDS segment + cndmask count advance — no ballot, no divergence,
// no SALU chain. wbuf[slot][tid] layout => bank index independent of the
// divergent slot (slot stride 2048 B = 0 mod 32 banks) => conflict-free.

// ---- pass A: pure read + branchless per-lane compact |x|>=2 ----------------
__global__ __launch_bounds__(THREADS, 4) void scan_kernel(const float* __restrict__ x,
                                                          unsigned* __restrict__ cand_count,
                                                          unsigned* __restrict__ row_oflow,
                                                          uint2* __restrict__ cand) {
    __shared__ uint2 wbuf[LANE_CAP][THREADS];   // 32 KiB; addr = s*2048 + t*8
    const int t = threadIdx.x;
    const int lane = t & 63;
    const int row = blockIdx.y;
    const int wbase = blockIdx.x * BLK_CHUNK + (t >> 6) * WAVE_CHUNK;
    const float4* src = (const float4*)(x + (size_t)row * ROW_N + wbase);
    unsigned cnt = 0;   // true per-lane candidate count (may exceed LANE_CAP)

    // all 16 coalesced loads in flight up front (64 VGPRs; 128-cap via launch_bounds)
    float4 v[16];
#pragma unroll
    for (int u = 0; u < 16; ++u) v[u] = src[u * 64 + lane];

#pragma unroll
    for (int u = 0; u < 16; ++u) {
        const unsigned fbase = (unsigned)(wbase + (u * 64 + lane) * 4);
        const unsigned bb[4] = {__float_as_uint(v[u].x), __float_as_uint(v[u].y),
                                __float_as_uint(v[u].z), __float_as_uint(v[u].w)};
#pragma unroll
        for (int c = 0; c < 4; ++c) {
            // unconditional write: garbage at slot cnt is overwritten by the
            // next true candidate (later in program order) or never read
            // (copy loop reads j < cnt). No branch, no exec churn.
            wbuf[cnt & (LANE_CAP - 1)][t] = make_uint2(fbase + (unsigned)c, bb[c]);
            cnt += ((bb[c] & 0x7FFFFFFFu) >= B0_BITS) ? 1u : 0u;
        }
    }

    // wave prefix-sum of per-lane counts (6 shuffle steps)
    unsigned incl = cnt;
#pragma unroll
    for (int d = 1; d < 64; d <<= 1) {
        const unsigned nv = __shfl_up(incl, d);
        if (lane >= d) incl += nv;
    }
    const unsigned excl = incl - cnt;
    const unsigned wtot = __shfl(incl, 63);
    // cnt == LANE_CAP already wrapped a garbage write onto slot 0 -> overflow
    const int of = __any(cnt >= (unsigned)LANE_CAP);

    unsigned base = 0;
    if (lane == 0) {
        base = atomicAdd(&cand_count[row], wtot);   // true count (n<K / cap detect)
        if (of) row_oflow[row] = 1u;
    }
    base = __shfl(base, 0);

    uint2* rcand = cand + (size_t)row * CAND_CAP;
    const unsigned m = cnt < (unsigned)LANE_CAP ? cnt : (unsigned)LANE_CAP;
    for (unsigned j = 0; j < m; ++j) {
        const unsigned g = base + excl + j;
        if (g < CAND_CAP) rcand[g] = wbuf[j][t];
    }
}

// -- select+scatter fused: per row, hist over candidates only, exact top-k -----
__global__ __launch_bounds__(THREADS_SS) void select_scatter_kernel(
        const uint2* __restrict__ cand, const unsigned* __restrict__ cand_count,
        const unsigned* __restrict__ row_oflow, const int* __restrict__ topk,
        float* __restrict__ out, int* __restrict__ row_flag) {
    const int row = blockIdx.x;
    const int t = threadIdx.x;
    const unsigned K = (unsigned)(*topk);
    const unsigned n = cand_count[row];
    const unsigned of = row_oflow[row];

    __shared__ unsigned h[NFB];          // 32 KiB fine-bucket hist
    __shared__ unsigned tidx[TIE_CAP];   // 8 KiB
    __shared__ unsigned tbits[TIE_CAP];  // 8 KiB
    __shared__ unsigned partial[THREADS_SS];
    __shared__ unsigned excl[THREADS_SS];
    __shared__ unsigned tcnt;
    __shared__ int sb, sneed;

    if (n < K || n > (unsigned)CAND_CAP || of) {   // block-uniform
        if (t == 0) row_flag[row] = 1;
        return;
    }
    for (int i = t; i < NFB; i += THREADS_SS) h[i] = 0;
    if (t == 0) tcnt = 0;
    __syncthreads();

    const uint2* rc = cand + (size_t)row * CAND_CAP;
    for (unsigned i = (unsigned)t; i < n; i += THREADS_SS) {
        const uint2 e = rc[i];
        atomicAdd(&h[((e.y & 0x7FFFFFFFu) >> FKSHIFT) - FB0], 1u);
    }
    __syncthreads();

    // suffix scan from the top fine bucket
    const int PER = NFB / THREADS_SS;   // 16
    unsigned s = 0;
#pragma unroll
    for (int i = 0; i < PER; ++i) s += h[NFB - 1 - (t * PER + i)];
    partial[t] = s;
    __syncthreads();
    if (t == 0) {
        unsigned c = 0;
        for (int i = 0; i < THREADS_SS; ++i) { excl[i] = c; c += partial[i]; }
    }
    __syncthreads();
    unsigned cum = excl[t];
#pragma unroll
    for (int i = 0; i < PER; ++i) {
        const int brel = NFB - 1 - (t * PER + i);
        const unsigned c = h[brel];
        if (cum < K && cum + c >= K) {   // unique crossing
            sb = brel + FB0;
            sneed = (int)(K - cum);
        }
        cum += c;
    }
    __syncthreads();
    const int b = sb;
    const int need = sneed;
    if (h[b - FB0] > (unsigned)TIE_CAP) {   // block-uniform; before any writes
        if (t == 0) row_flag[row] = 1;
        return;
    }

    // scatter winners above the tie bucket; collect ties
    float* rout = out + (size_t)row * ROW_N;
    for (unsigned i = (unsigned)t; i < n; i += THREADS_SS) {
        const uint2 e = rc[i];
        const int fk = (int)((e.y & 0x7FFFFFFFu) >> FKSHIFT);
        if (fk > b) {
            rout[e.x] = __uint_as_float(e.y);
        } else if (fk == b) {
            const unsigned p = atomicAdd(&tcnt, 1u);
            tidx[p] = e.x; tbits[p] = e.y;   // p < TIE_CAP guaranteed (hist check)
        }
    }
    __syncthreads();

    // exact rank among ties: desc |x| bits, asc index (matches lax.top_k)
    const int c = (int)tcnt;
    for (int i = t; i < c; i += THREADS_SS) {
        const unsigned bits = tbits[i], idx = tidx[i];
        const uint64_t key = ((uint64_t)(bits & 0x7FFFFFFFu) << 32) | (uint64_t)(~idx);
        int rank = 0;
        for (int j = 0; j < c; ++j) {
            const uint64_t kj = ((uint64_t)(tbits[j] & 0x7FFFFFFFu) << 32) | (uint64_t)(~tidx[j]);
            rank += (kj > key) ? 1 : 0;
        }
        if (rank < need) rout[idx] = __uint_as_float(bits);
    }
}

// ---- fallback: self-contained exact solve for flagged rows (normally no-op) --
__global__ __launch_bounds__(THREADS) void fallback_kernel(const float* __restrict__ x,
                                                           float* __restrict__ out,
                                                           const int* __restrict__ topk,
                                                           const int* __restrict__ row_flag) {
    const int row = blockIdx.x;
    if (!row_flag[row]) return;
    const int t = threadIdx.x;
    const unsigned K = (unsigned)(*topk);
    const float4* xr = (const float4*)(x + (size_t)row * ROW_N);
    float* rout = out + (size_t)row * ROW_N;   // already zero-filled by memset

    __shared__ unsigned h[NBUCKET];          // 16 KiB coarse hist
    __shared__ unsigned tidx[FB_TIE_CAP];    // 16 KiB
    __shared__ unsigned tbits[FB_TIE_CAP];   // 16 KiB
    __shared__ unsigned partial[THREADS];
    __shared__ unsigned excl[THREADS];
    __shared__ unsigned tcnt;
    __shared__ int sb, sneed;
    for (int i = t; i < NBUCKET; i += THREADS) h[i] = 0;
    if (t == 0) tcnt = 0;
    __syncthreads();

    for (int i4 = t; i4 < ROW_N / 4; i4 += THREADS) {
        const float4 v = xr[i4];
        atomicAdd(&h[(__float_as_uint(v.x) & 0x7FFFFFFFu) >> KSHIFT], 1u);
        atomicAdd(&h[(__float_as_uint(v.y) & 0x7FFFFFFFu) >> KSHIFT], 1u);
        atomicAdd(&h[(__float_as_uint(v.z) & 0x7FFFFFFFu) >> KSHIFT], 1u);
        atomicAdd(&h[(__float_as_uint(v.w) & 0x7FFFFFFFu) >> KSHIFT], 1u);
    }
    __syncthreads();

    const int PER = NBUCKET / THREADS;   // 16
    unsigned s = 0;
#pragma unroll
    for (int i = 0; i < PER; ++i) s += h[NBUCKET - 1 - (t * PER + i)];
    partial[t] = s;
    __syncthreads();
    if (t == 0) {
        unsigned c = 0;
        for (int i = 0; i < THREADS; ++i) { excl[i] = c; c += partial[i]; }
    }
    __syncthreads();
    unsigned cum = excl[t];
#pragma unroll
    for (int i = 0; i < PER; ++i) {
        const int bucket = NBUCKET - 1 - (t * PER + i);
        const unsigned c = h[bucket];
        if (cum < K && cum + c >= K) { sb = bucket; sneed = (int)(K - cum); }
        cum += c;
    }
    __syncthreads();
    const int b = sb;
    const int need = sneed;

    for (int i4 = t; i4 < ROW_N / 4; i4 += THREADS) {
        const float4 v = xr[i4];
        const unsigned bits4[4] = {__float_as_uint(v.x), __float_as_uint(v.y),
                                   __float_as_uint(v.z), __float_as_uint(v.w)};
#pragma unroll
        for (int c = 0; c < 4; ++c) {
            const int key = (int)((bits4[c] & 0x7FFFFFFFu) >> KSHIFT);
            if (key > b) {
                rout[i4 * 4 + c] = __uint_as_float(bits4[c]);
            } else if (key == b) {
                const unsigned p = atomicAdd(&tcnt, 1u);
                if (p < FB_TIE_CAP) { tidx[p] = (unsigned)(i4 * 4 + c); tbits[p] = bits4[c]; }
            }
        }
    }
    __syncthreads();
    const int c = (int)(tcnt < (unsigned)FB_TIE_CAP ? tcnt : (unsigned)FB_TIE_CAP);
    for (int i = t; i < c; i += THREADS) {
        const unsigned bits = tbits[i], idx = tidx[i];
        const uint64_t key = ((uint64_t)(bits & 0x7FFFFFFFu) << 32) | (uint64_t)(~idx);
        int rank = 0;
        for (int j = 0; j < c; ++j) {
            const uint64_t kj = ((uint64_t)(tbits[j] & 0x7FFFFFFFu) << 32) | (uint64_t)(~tidx[j]);
            rank += (kj > key) ? 1 : 0;
        }
        if (rank < need) rout[idx] = __uint_as_float(bits);
    }
}

extern "C" void kernel_launch(void* const* d_in, const int* in_sizes, int n_in,
                              void* d_out, int out_size, void* d_ws, size_t ws_size,
                              hipStream_t stream) {
    const float* x = (const float*)d_in[0];
    const int* topk = (const int*)d_in[1];
    float* out = (float*)d_out;
    char* ws = (char*)d_ws;

    unsigned* cand_count = (unsigned*)(ws + OFF_CNT);
    unsigned* row_oflow  = (unsigned*)(ws + OFF_OFL);
    int* row_flag        = (int*)(ws + OFF_FLG);
    uint2* cand          = (uint2*)(ws + OFF_CAND);

    // zero counters + flags (ws is re-poisoned to 0xAA before each run)
    hipMemsetAsync(ws, 0, MEMSET_BYTES, stream);
    // zero-fill the output via the rocclr fill path (measured 6.8 TB/s in R3)
    hipMemsetAsync(out, 0, (size_t)B * ROW_N * sizeof(float), stream);

    dim3 gridA(BLOCKS_PER_ROW, B);  // 16 x 128 = 2048 blocks
    scan_kernel<<<gridA, THREADS, 0, stream>>>(x, cand_count, row_oflow, cand);
    select_scatter_kernel<<<B, THREADS_SS, 0, stream>>>(cand, cand_count, row_oflow,
                                                        topk, out, row_flag);
    fallback_kernel<<<B, THREADS, 0, stream>>>(x, out, topk, row_flag);
}

// Round 5
// 108.587 us; speedup vs baseline: 1.0663x; 1.0663x over previous
//
#include <hip/hip_runtime.h>
#include <stdint.h>

// Problem constants (fixed by the reference): x is (128,1,512,512) fp32, k=2048.
#define B        128
#define ROW_N    262144                 // 512*512 elements per row
#define THREADS  256
#define BLOCKS_PER_ROW 16
#define BLK_CHUNK (ROW_N / BLOCKS_PER_ROW)   // 16384 floats per block
#define WAVE_CHUNK 4096                      // floats per wave (4 waves/block)
#define WAVE_CAP 512                         // per-wave candidate cap (mean 184, +25 sigma)

// Speculative exact pre-filter: keep ALL elements with |x| >= 2.0.
// For the fixed N(0,1) input: k-th |x| ~= 2.66; >=2.0 population ~11.9k +- 107
// per row. n >= K guarantees the exact top-k lies within the candidate set.
// Any violation (per-wave cap, row cap, n < K) flags the row -> exact fallback.
#define B0_BITS  0x40000000u  // bit pattern of 2.0f (abs-bits compare)
#define CAND_CAP 16384        // per-row candidate capacity (+41 sigma)
#define FKSHIFT  17           // 14-bit fine key for tie resolution
#define FB0      8192         // (B0_BITS >> FKSHIFT)
#define NFB      8192         // fine buckets [8192, 16384)
#define TIE_CAP  2048         // ties in one fine bucket (mean ~190)
#define THREADS_SS 512        // select_scatter block size
// fallback (normally never runs)
#define KSHIFT   19
#define NBUCKET  4096
#define FB_TIE_CAP 4096

// workspace layout (bytes)
#define OFF_CNT  0                         // per-row candidate counters (B u32)
#define OFF_OFL  512                       // per-row overflow flags (B u32)
#define OFF_FLG  1024                      // per-row fallback flag (B int)
#define OFF_CAND 4096                      // B * CAND_CAP * uint2 = 16 MiB
#define MEMSET_BYTES 1536

typedef float vfloat4 __attribute__((ext_vector_type(4)));

// R5 theory: every scan variant (R0-R4: ballot/branchless/hoisted/NT/cached/
// split) read x at ~1.8 TB/s, while the grid-stride rocclr fill sustains
// 6.8 TB/s. The invariant in our kernels is the ALIGNED POWER-OF-2 CHUNKING:
// 64KB/block, 16KB/wave, rows 1MB apart. Memory-paced progress keeps all
// 8192 waves at the SAME offset within their chunks, so concurrent addresses
// are congruent mod large pow2 -> they collapse onto a few HBM channels.
// Latency-sensitive reads queue per-channel and throughput dies; writes
// (fire-and-forget) barely care — which is why all write-side experiments
// were null. Fix: rotate each wave's 16x1KB access ORDER by a per-wave hash.
// Same bytes, same coalescing, decorrelated instantaneous address stream.

// ---- pass A: ONE barrier-free fused pass: zero-fill out + compact |x|>=2 ----
__global__ __launch_bounds__(THREADS) void scan_zero_kernel(const float* __restrict__ x,
                                                            float* __restrict__ out,
                                                            unsigned* __restrict__ cand_count,
                                                            unsigned* __restrict__ row_oflow,
                                                            uint2* __restrict__ cand) {
    __shared__ uint2 wbuf[THREADS / 64][WAVE_CAP];   // 16 KiB, wave-private slices
    const int t = threadIdx.x;
    const int w = t >> 6;
    const int lane = t & 63;
    const unsigned long long lt = (1ull << lane) - 1ull;
    const int row = blockIdx.y;
    const int wbase = blockIdx.x * BLK_CHUNK + w * WAVE_CHUNK;  // float offset in row
    const float4* src = (const float4*)(x + (size_t)row * ROW_N + wbase);
    vfloat4* dst = (vfloat4*)(out + (size_t)row * ROW_N + wbase);
    uint2* wb = wbuf[w];
    unsigned wcnt = 0;   // wave-uniform (derived from ballots only)
    const vfloat4 z = {0.f, 0.f, 0.f, 0.f};

    // per-wave rotation of the 16-segment access order (channel decorrelation)
    const unsigned gw = (unsigned)((row * BLOCKS_PER_ROW + (int)blockIdx.x) * 4 + w);
    const unsigned s = (gw * 2654435761u) >> 28;   // Fibonacci hash -> 0..15

    // all 16 coalesced 1KB loads in flight up front, in rotated order
    float4 v[16];
#pragma unroll
    for (int i = 0; i < 16; ++i) {
        const unsigned u = (s + (unsigned)i) & 15u;
        v[i] = src[u * 64 + lane];
    }

#pragma unroll
    for (int i = 0; i < 16; ++i) {
        const unsigned u = (s + (unsigned)i) & 15u;
        const unsigned fbase = (unsigned)(wbase + (u * 64 + (unsigned)lane) * 4);
        const unsigned bb[4] = {__float_as_uint(v[i].x), __float_as_uint(v[i].y),
                                __float_as_uint(v[i].z), __float_as_uint(v[i].w)};
#pragma unroll
        for (int c = 0; c < 4; ++c) {
            const bool pred = (bb[c] & 0x7FFFFFFFu) >= B0_BITS;   // ~4.5%
            const unsigned long long mask = __ballot(pred);
            if (pred) {
                const unsigned p = wcnt + (unsigned)__popcll(mask & lt);
                if (p < WAVE_CAP) wb[p] = make_uint2(fbase + (unsigned)c, bb[c]);
            }
            wcnt += (unsigned)__popcll(mask);
        }
        // zero-store the processed segment (same rotated order as the loads)
        dst[u * 64 + lane] = z;
    }

    // final flush: one global atomic per wave
    const unsigned total = wcnt < WAVE_CAP ? wcnt : WAVE_CAP;
    unsigned base = 0;
    if (lane == 0) {
        base = atomicAdd(&cand_count[row], wcnt);   // true count (gap/oflow detect)
        if (wcnt > WAVE_CAP) row_oflow[row] = 1u;
    }
    base = __shfl(base, 0);
    uint2* rcand = cand + (size_t)row * CAND_CAP;
    for (unsigned i = (unsigned)lane; i < total; i += 64) {
        const unsigned gpos = base + i;
        if (gpos < CAND_CAP) rcand[gpos] = wb[i];
    }
}

// -- select+scatter fused: per row, hist over candidates only, exact top-k -----
__global__ __launch_bounds__(THREADS_SS) void select_scatter_kernel(
        const uint2* __restrict__ cand, const unsigned* __restrict__ cand_count,
        const unsigned* __restrict__ row_oflow, const int* __restrict__ topk,
        float* __restrict__ out, int* __restrict__ row_flag) {
    const int row = blockIdx.x;
    const int t = threadIdx.x;
    const unsigned K = (unsigned)(*topk);
    const unsigned n = cand_count[row];
    const unsigned of = row_oflow[row];

    __shared__ unsigned h[NFB];          // 32 KiB fine-bucket hist
    __shared__ unsigned tidx[TIE_CAP];   // 8 KiB
    __shared__ unsigned tbits[TIE_CAP];  // 8 KiB
    __shared__ unsigned partial[THREADS_SS];
    __shared__ unsigned excl[THREADS_SS];
    __shared__ unsigned tcnt;
    __shared__ int sb, sneed;

    if (n < K || n > (unsigned)CAND_CAP || of) {   // block-uniform
        if (t == 0) row_flag[row] = 1;
        return;
    }
    for (int i = t; i < NFB; i += THREADS_SS) h[i] = 0;
    if (t == 0) tcnt = 0;
    __syncthreads();

    const uint2* rc = cand + (size_t)row * CAND_CAP;
    for (unsigned i = (unsigned)t; i < n; i += THREADS_SS) {
        const uint2 e = rc[i];
        atomicAdd(&h[((e.y & 0x7FFFFFFFu) >> FKSHIFT) - FB0], 1u);
    }
    __syncthreads();

    // suffix scan from the top fine bucket
    const int PER = NFB / THREADS_SS;   // 16
    unsigned s = 0;
#pragma unroll
    for (int i = 0; i < PER; ++i) s += h[NFB - 1 - (t * PER + i)];
    partial[t] = s;
    __syncthreads();
    if (t == 0) {
        unsigned c = 0;
        for (int i = 0; i < THREADS_SS; ++i) { excl[i] = c; c += partial[i]; }
    }
    __syncthreads();
    unsigned cum = excl[t];
#pragma unroll
    for (int i = 0; i < PER; ++i) {
        const int brel = NFB - 1 - (t * PER + i);
        const unsigned c = h[brel];
        if (cum < K && cum + c >= K) {   // unique crossing
            sb = brel + FB0;
            sneed = (int)(K - cum);
        }
        cum += c;
    }
    __syncthreads();
    const int b = sb;
    const int need = sneed;
    if (h[b - FB0] > (unsigned)TIE_CAP) {   // block-uniform; before any writes
        if (t == 0) row_flag[row] = 1;
        return;
    }

    // scatter winners above the tie bucket; collect ties
    float* rout = out + (size_t)row * ROW_N;
    for (unsigned i = (unsigned)t; i < n; i += THREADS_SS) {
        const uint2 e = rc[i];
        const int fk = (int)((e.y & 0x7FFFFFFFu) >> FKSHIFT);
        if (fk > b) {
            rout[e.x] = __uint_as_float(e.y);
        } else if (fk == b) {
            const unsigned p = atomicAdd(&tcnt, 1u);
            tidx[p] = e.x; tbits[p] = e.y;   // p < TIE_CAP guaranteed (hist check)
        }
    }
    __syncthreads();

    // exact rank among ties: desc |x| bits, asc index (matches lax.top_k)
    const int c = (int)tcnt;
    for (int i = t; i < c; i += THREADS_SS) {
        const unsigned bits = tbits[i], idx = tidx[i];
        const uint64_t key = ((uint64_t)(bits & 0x7FFFFFFFu) << 32) | (uint64_t)(~idx);
        int rank = 0;
        for (int j = 0; j < c; ++j) {
            const uint64_t kj = ((uint64_t)(tbits[j] & 0x7FFFFFFFu) << 32) | (uint64_t)(~tidx[j]);
            rank += (kj > key) ? 1 : 0;
        }
        if (rank < need) rout[idx] = __uint_as_float(bits);
    }
}

// ---- fallback: self-contained exact solve for flagged rows (normally no-op) --
__global__ __launch_bounds__(THREADS) void fallback_kernel(const float* __restrict__ x,
                                                           float* __restrict__ out,
                                                           const int* __restrict__ topk,
                                                           const int* __restrict__ row_flag) {
    const int row = blockIdx.x;
    if (!row_flag[row]) return;
    const int t = threadIdx.x;
    const unsigned K = (unsigned)(*topk);
    const float4* xr = (const float4*)(x + (size_t)row * ROW_N);
    float* rout = out + (size_t)row * ROW_N;   // already zero-filled by scan_zero

    __shared__ unsigned h[NBUCKET];          // 16 KiB coarse hist
    __shared__ unsigned tidx[FB_TIE_CAP];    // 16 KiB
    __shared__ unsigned tbits[FB_TIE_CAP];   // 16 KiB
    __shared__ unsigned partial[THREADS];
    __shared__ unsigned excl[THREADS];
    __shared__ unsigned tcnt;
    __shared__ int sb, sneed;
    for (int i = t; i < NBUCKET; i += THREADS) h[i] = 0;
    if (t == 0) tcnt = 0;
    __syncthreads();

    for (int i4 = t; i4 < ROW_N / 4; i4 += THREADS) {
        const float4 v = xr[i4];
        atomicAdd(&h[(__float_as_uint(v.x) & 0x7FFFFFFFu) >> KSHIFT], 1u);
        atomicAdd(&h[(__float_as_uint(v.y) & 0x7FFFFFFFu) >> KSHIFT], 1u);
        atomicAdd(&h[(__float_as_uint(v.z) & 0x7FFFFFFFu) >> KSHIFT], 1u);
        atomicAdd(&h[(__float_as_uint(v.w) & 0x7FFFFFFFu) >> KSHIFT], 1u);
    }
    __syncthreads();

    const int PER = NBUCKET / THREADS;   // 16
    unsigned s = 0;
#pragma unroll
    for (int i = 0; i < PER; ++i) s += h[NBUCKET - 1 - (t * PER + i)];
    partial[t] = s;
    __syncthreads();
    if (t == 0) {
        unsigned c = 0;
        for (int i = 0; i < THREADS; ++i) { excl[i] = c; c += partial[i]; }
    }
    __syncthreads();
    unsigned cum = excl[t];
#pragma unroll
    for (int i = 0; i < PER; ++i) {
        const int bucket = NBUCKET - 1 - (t * PER + i);
        const unsigned c = h[bucket];
        if (cum < K && cum + c >= K) { sb = bucket; sneed = (int)(K - cum); }
        cum += c;
    }
    __syncthreads();
    const int b = sb;
    const int need = sneed;

    for (int i4 = t; i4 < ROW_N / 4; i4 += THREADS) {
        const float4 v = xr[i4];
        const unsigned bits4[4] = {__float_as_uint(v.x), __float_as_uint(v.y),
                                   __float_as_uint(v.z), __float_as_uint(v.w)};
#pragma unroll
        for (int c = 0; c < 4; ++c) {
            const int key = (int)((bits4[c] & 0x7FFFFFFFu) >> KSHIFT);
            if (key > b) {
                rout[i4 * 4 + c] = __uint_as_float(bits4[c]);
            } else if (key == b) {
                const unsigned p = atomicAdd(&tcnt, 1u);
                if (p < FB_TIE_CAP) { tidx[p] = (unsigned)(i4 * 4 + c); tbits[p] = bits4[c]; }
            }
        }
    }
    __syncthreads();
    const int c = (int)(tcnt < (unsigned)FB_TIE_CAP ? tcnt : (unsigned)FB_TIE_CAP);
    for (int i = t; i < c; i += THREADS) {
        const unsigned bits = tbits[i], idx = tidx[i];
        const uint64_t key = ((uint64_t)(bits & 0x7FFFFFFFu) << 32) | (uint64_t)(~idx);
        int rank = 0;
        for (int j = 0; j < c; ++j) {
            const uint64_t kj = ((uint64_t)(tbits[j] & 0x7FFFFFFFu) << 32) | (uint64_t)(~tidx[j]);
            rank += (kj > key) ? 1 : 0;
        }
        if (rank < need) rout[idx] = __uint_as_float(bits);
    }
}

extern "C" void kernel_launch(void* const* d_in, const int* in_sizes, int n_in,
                              void* d_out, int out_size, void* d_ws, size_t ws_size,
                              hipStream_t stream) {
    const float* x = (const float*)d_in[0];
    const int* topk = (const int*)d_in[1];
    float* out = (float*)d_out;
    char* ws = (char*)d_ws;

    unsigned* cand_count = (unsigned*)(ws + OFF_CNT);
    unsigned* row_oflow  = (unsigned*)(ws + OFF_OFL);
    int* row_flag        = (int*)(ws + OFF_FLG);
    uint2* cand          = (uint2*)(ws + OFF_CAND);

    // zero counters + flags only (ws is re-poisoned to 0xAA before each run)
    hipMemsetAsync(ws, 0, MEMSET_BYTES, stream);

    dim3 gridA(BLOCKS_PER_ROW, B);  // 16 x 128 = 2048 blocks
    scan_zero_kernel<<<gridA, THREADS, 0, stream>>>(x, out, cand_count, row_oflow, cand);
    select_scatter_kernel<<<B, THREADS_SS, 0, stream>>>(cand, cand_count, row_oflow,
                                                        topk, out, row_flag);
    fallback_kernel<<<B, THREADS, 0, stream>>>(x, out, topk, row_flag);
}